// Round 9
// baseline (29431.302 us; speedup 1.0000x reference)
//
#include <hip/hip_runtime.h>
#include <hip/hip_bf16.h>
#include <stdint.h>

#define SEQ   512
#define BATCH 2048
#define HID   512
#define XF    31

typedef __bf16 bf16_t;
typedef bf16_t bf16x8 __attribute__((ext_vector_type(8)));
typedef bf16_t bf16x4 __attribute__((ext_vector_type(4)));
typedef float  f32x4  __attribute__((ext_vector_type(4)));

// async global->LDS, 16B per lane; LDS dest = wave-uniform base + lane*16
__device__ __forceinline__ void gload16(const void* g, void* lds) {
    __builtin_amdgcn_global_load_lds(
        (const __attribute__((address_space(1))) void*)g,
        (__attribute__((address_space(3))) void*)lds,
        16, 0, 0);
}

__device__ __forceinline__ float sigmoid_f(float x) {
    return 1.f / (1.f + __expf(-x));
}
__device__ __forceinline__ float tanh_f(float x) {
    float e = __expf(2.f * x);
    return 1.f - 2.f / (e + 1.f);
}

// ---------------- prologue kernels (run once per launch) -------------------
__global__ void prep_w(const float* __restrict__ W_ih, const float* __restrict__ W_hh,
                       bf16_t* __restrict__ Wcat) {
    const int j = blockIdx.x;                 // 0..2047 (gate row)
    for (int k = threadIdx.x; k < 1024; k += 256) {
        float v = (k < 512) ? W_ih[(size_t)j * 512 + k]
                            : W_hh[(size_t)j * 512 + (k - 512)];
        Wcat[(size_t)j * 1024 + k] = (bf16_t)v;
    }
}

__global__ void prep_state(const float* __restrict__ h0,
                           bf16_t* __restrict__ H0, float* __restrict__ out_all,
                           unsigned* __restrict__ bar) {
    const int b = blockIdx.x;                 // 0..2047
    for (int d = threadIdx.x; d < 512; d += 256) {
        H0[(size_t)b * 512 + d] = (bf16_t)h0[(size_t)b * 512 + d];
        out_all[(size_t)b * 512 + d] = 0.f;   // zeroes whole [SEQ][B] output
    }
    if (blockIdx.x == 0 && threadIdx.x < 16) bar[threadIdx.x] = 0u;
}

__global__ void prep_bias(const float* __restrict__ b_ih, const float* __restrict__ b_hh,
                          float* __restrict__ bg) {
    int j = blockIdx.x * 256 + threadIdx.x;
    bg[j] = b_ih[j] + b_hh[j];
}

// W_in split into bf16 hi + lo residual (for f32-grade X0 via 3 MFMAs)
__global__ void prep_wb(const float* __restrict__ W_in,
                        bf16_t* __restrict__ Wbh, bf16_t* __restrict__ Wbl) {
    int idx = blockIdx.x * 256 + threadIdx.x;   // 0..16383 = 512*32
    float v = W_in[idx];
    bf16_t h = (bf16_t)v;
    Wbh[idx] = h;
    Wbl[idx] = (bf16_t)(v - (float)h);
}

// ---------------- persistent kernel: all 512 timesteps ---------------------
// PLAIN launch (not cooperative): 256 blocks x 512 thr, 160 KB LDS ->
// exactly 1 block/CU on 256 CUs -> all blocks resident by construction.
// (R8's hipLaunchCooperativeKernel was the suspected container-killer:
// coop validation / graph-capture interaction. Plain launches captured
// fine in rounds 0-7.)
// Cross-step sync: GROUP-LOCAL barrier over the 16 blocks sharing mb (the
// only blocks exchanging data: H rows + y atomics), monotonic counter
// bar[mb], agent-scope release/acquire. The spin is TIMEOUT-BOUNDED: if the
// counter never arrives (co-residency/visibility failure), blocks bail and
// finish with garbage instead of hanging the container -> visible failure.
// Per step: phase 1 (Hin @ W_hh, depth-2 counted-vmcnt pipeline), phase B
// (X0 built in LDS from register-resident W_in frags), phase 2 (X0 @ W_ih),
// epilogue (Gs k-reduce + cell, cell state in registers all sequence).
__global__ __launch_bounds__(512, 1) void step_persist(
    const float*  __restrict__ x_all,  // [SEQ][B][31]
    const float*  __restrict__ y0,     // [B]
    const bf16_t* __restrict__ Wbh,    // [512][32] bf16 hi
    const bf16_t* __restrict__ Wbl,    // [512][32] bf16 lo residual
    const float*  __restrict__ b_in,   // [512]
    const float*  __restrict__ c0,     // [B][512] f32
    bf16_t*       __restrict__ Hb0,    // [B][512] bf16 (ping)
    bf16_t*       __restrict__ Hb1,    // [B][512] bf16 (pong)
    const bf16_t* __restrict__ Wcat,   // [2048][1024]
    const float*  __restrict__ b_gate, // [2048]
    const float*  __restrict__ W_out,  // [512]
    const float*  __restrict__ b_out,  // [1]
    float*        __restrict__ out,    // [SEQ][B] (pre-zeroed)
    unsigned*     __restrict__ bar)    // [16] group barrier counters
{
    __shared__ __align__(16) char smem[163840];
    // [0,131072): phase-1 As[4](@0)+Bs[4](@65536); then X0L[128][512] bf16;
    //             then Gs0(@0)/Gs1(@65536) f32 overlays
    // [131072,163840): phase-2 Bd[2] (16 KiB each)
    float (*Gs0)[128] = (float (*)[128])smem;
    float (*Gs1)[128] = (float (*)[128])(smem + 65536);

    const int tid  = threadIdx.x;
    const int lane = tid & 63;
    const int wid  = tid >> 6;        // 0..7
    const int wm   = wid >> 2;        // 0..1 (m half: 64 rows)
    const int wn   = (wid >> 1) & 1;  // 0..1 (n half: 64 cols)
    const int wk   = wid & 1;         // 0..1 (k half of BK=64)

    // XCD-stable decode: bid = xcd + 8*slot; XCD (xm,xn) on a 4x2 grid
    const int bid  = blockIdx.x;      // 0..255
    const int xcd  = bid & 7;
    const int slot = bid >> 3;        // 0..31
    const int mb   = (xcd >> 1) * 4 + (slot & 3);   // 0..15
    const int nb   = (xcd & 1) * 8 + (slot >> 2);   // 0..15

    const int r  = lane & 15, q = lane >> 4;
    const int lr  = lane >> 3;                        // row-in-8 for staging
    const int lcs = ((lane & 7) ^ lr) * 8;            // swizzled SOURCE k-chunk
    const int kob = (((wk << 2) + q) ^ (r & 7)) * 16; // swizzled read col (bytes)

    // ---- persistent per-thread state (whole sequence) --------------------
    bf16x8 wfh[4], wfl[4];
    float4 bi4[4];
#pragma unroll
    for (int u = 0; u < 4; ++u) {
        const int dt = wid * 4 + u;
        const size_t wo_ = (size_t)(dt * 16 + r) * 32 + q * 8;
        wfh[u] = *(const bf16x8*)&Wbh[wo_];
        wfl[u] = *(const bf16x8*)&Wbl[wo_];
        bi4[u] = *(const float4*)&b_in[dt * 16 + q * 4];
    }
    const int row_e   = tid >> 2;          // 0..127
    const int dq      = (tid & 3) * 8;     // 0..24
    const int b_glob  = mb * 128 + row_e;
    float cv[8], wo[8];
    *(float4*)&cv[0] = *(const float4*)&c0[(size_t)b_glob * 512 + nb * 32 + dq];
    *(float4*)&cv[4] = *(const float4*)&c0[(size_t)b_glob * 512 + nb * 32 + dq + 4];
    *(float4*)&wo[0] = *(const float4*)&W_out[nb * 32 + dq];
    *(float4*)&wo[4] = *(const float4*)&W_out[nb * 32 + dq + 4];
    const float bo = b_out[0];
    int bailed = 0;

    const bf16_t* Hin = Hb0;   // updated per step
#define STAGE_AB(dst, kt)                                                     \
    {                                                                          \
        const int k0 = ((kt) - 8) * 64;                                        \
        _Pragma("unroll")                                                      \
        for (int iss = 0; iss < 2; ++iss) {                                    \
            const int r0 = wid * 16 + iss * 8;                                 \
            gload16(Hin + (size_t)(mb * 128 + r0 + lr) * 512 + k0 + lcs,       \
                    smem + (size_t)(dst) * 16384 + r0 * 128);                  \
        }                                                                      \
        _Pragma("unroll")                                                      \
        for (int iss = 0; iss < 2; ++iss) {                                    \
            const int r0   = wid * 16 + iss * 8;                               \
            const int nloc = r0 + lr;                                          \
            const int j    = (nloc >> 5) * 512 + nb * 32 + (nloc & 31);        \
            gload16(Wcat + (size_t)j * 1024 + (kt) * 64 + lcs,                 \
                    smem + 65536 + (size_t)(dst) * 16384 + r0 * 128);          \
        }                                                                      \
    }
#define STAGE_B2(dst, kt)                                                     \
    {                                                                          \
        _Pragma("unroll")                                                      \
        for (int iss = 0; iss < 2; ++iss) {                                    \
            const int r0   = wid * 16 + iss * 8;                               \
            const int nloc = r0 + lr;                                          \
            const int j    = (nloc >> 5) * 512 + nb * 32 + (nloc & 31);        \
            gload16(Wcat + (size_t)j * 1024 + (kt) * 64 + lcs,                 \
                    smem + 131072 + (size_t)(dst) * 16384 + r0 * 128);         \
        }                                                                      \
    }

#pragma unroll 1
    for (int t = 0; t < SEQ; ++t) {
        const float* x_t   = x_all + (size_t)t * BATCH * XF;
        const float* yprev = (t == 0) ? y0 : (out + (size_t)(t - 1) * BATCH);
        float*       yout  = out + (size_t)t * BATCH;
        Hin                = (t & 1) ? Hb1 : Hb0;
        bf16_t*      Hout  = (t & 1) ? Hb0 : Hb1;

        // ---- early: x(+y) B-fragments for all 8 batch groups, hi/lo split
        bf16x8 xh[8], xl[8];
#pragma unroll
        for (int g = 0; g < 8; ++g) {
            const int row = mb * 128 + g * 16 + r;
            const float* bp = x_t + (size_t)row * XF + q * 8;
            float tmp[8];
#pragma unroll
            for (int j = 0; j < 7; ++j) tmp[j] = bp[j];
            const float* p7 = (q == 3) ? (yprev + row) : (bp + 7);
            tmp[7] = *p7;
#pragma unroll
            for (int j = 0; j < 8; ++j) {
                bf16_t h = (bf16_t)tmp[j];
                xh[g][j] = h;
                xl[g][j] = (bf16_t)(tmp[j] - (float)h);
            }
        }

        f32x4 acc[4][4];
#pragma unroll
        for (int mi = 0; mi < 4; ++mi)
#pragma unroll
            for (int ni = 0; ni < 4; ++ni) {
                f32x4 z = {0.f, 0.f, 0.f, 0.f};
                acc[mi][ni] = z;
            }

        // ============= phase 1: kt 8..15 (Hin x W_hh) ======================
        STAGE_AB(0, 8);
        STAGE_AB(1, 9);
#pragma unroll
        for (int kt = 8; kt < 16; ++kt) {
            if (kt + 2 < 16) STAGE_AB((kt + 2) & 3, kt + 2);
            if (kt < 14) {
                asm volatile("s_waitcnt vmcnt(8)" ::: "memory");
            } else if (kt == 14) {
                asm volatile("s_waitcnt vmcnt(4)" ::: "memory");
            } else {
                asm volatile("s_waitcnt vmcnt(0)" ::: "memory");
            }
            __builtin_amdgcn_s_barrier();
            __builtin_amdgcn_sched_barrier(0);

            const int cur = kt & 3;
            const char* Ab = smem + (size_t)cur * 16384;
            const char* Bb = smem + 65536 + (size_t)cur * 16384;
            bf16x8 af[4], bfr[4];
#pragma unroll
            for (int mi = 0; mi < 4; ++mi)
                af[mi] = *(const bf16x8*)(Ab + (wm * 64 + mi * 16 + r) * 128 + kob);
#pragma unroll
            for (int ni = 0; ni < 4; ++ni)
                bfr[ni] = *(const bf16x8*)(Bb + (wn * 64 + ni * 16 + r) * 128 + kob);
#pragma unroll
            for (int mi = 0; mi < 4; ++mi)
#pragma unroll
                for (int ni = 0; ni < 4; ++ni)
                    acc[mi][ni] = __builtin_amdgcn_mfma_f32_16x16x32_bf16(
                        af[mi], bfr[ni], acc[mi][ni], 0, 0, 0);
        }

        __syncthreads();   // phase-1 LDS reads done; [0,128K) free for X0L

        // ============= phase B: build X0 slice in LDS ======================
        STAGE_B2(0, 0);
        STAGE_B2(1, 1);
#pragma unroll
        for (int u = 0; u < 4; ++u) {
            const int dt = wid * 4 + u;
#pragma unroll
            for (int g = 0; g < 8; ++g) {
                f32x4 pa = {0.f, 0.f, 0.f, 0.f};
                pa = __builtin_amdgcn_mfma_f32_16x16x32_bf16(wfh[u], xh[g], pa, 0, 0, 0);
                pa = __builtin_amdgcn_mfma_f32_16x16x32_bf16(wfh[u], xl[g], pa, 0, 0, 0);
                pa = __builtin_amdgcn_mfma_f32_16x16x32_bf16(wfl[u], xh[g], pa, 0, 0, 0);
                bf16x4 hv;
                hv[0] = (bf16_t)fmaxf(pa[0] + bi4[u].x, 0.f);
                hv[1] = (bf16_t)fmaxf(pa[1] + bi4[u].y, 0.f);
                hv[2] = (bf16_t)fmaxf(pa[2] + bi4[u].z, 0.f);
                hv[3] = (bf16_t)fmaxf(pa[3] + bi4[u].w, 0.f);
                const int c  = dt * 2 + (q >> 1);
                const int cs = (c & ~7) | ((c & 7) ^ (r & 7));
                *(bf16x4*)(smem + (size_t)(g * 16 + r) * 1024 + cs * 16 + (q & 1) * 8) = hv;
            }
        }

        __syncthreads();   // X0L complete (also covers Bd[0],Bd[1] staging)

        // ============= phase 2: kt 0..7 (X0 x W_ih) ========================
#pragma unroll
        for (int kt = 0; kt < 8; ++kt) {
            if (kt < 7) {
                asm volatile("s_waitcnt vmcnt(2)" ::: "memory");
            } else {
                asm volatile("s_waitcnt vmcnt(0)" ::: "memory");
            }
            __builtin_amdgcn_s_barrier();
            __builtin_amdgcn_sched_barrier(0);

            const char* Bb = smem + 131072 + (size_t)(kt & 1) * 16384;
            bf16x8 af[4], bfr[4];
#pragma unroll
            for (int mi = 0; mi < 4; ++mi)
                af[mi] = *(const bf16x8*)(smem + (size_t)(wm * 64 + mi * 16 + r) * 1024
                                          + kt * 128 + kob);
#pragma unroll
            for (int ni = 0; ni < 4; ++ni)
                bfr[ni] = *(const bf16x8*)(Bb + (wn * 64 + ni * 16 + r) * 128 + kob);
#pragma unroll
            for (int mi = 0; mi < 4; ++mi)
#pragma unroll
                for (int ni = 0; ni < 4; ++ni)
                    acc[mi][ni] = __builtin_amdgcn_mfma_f32_16x16x32_bf16(
                        af[mi], bfr[ni], acc[mi][ni], 0, 0, 0);
            __builtin_amdgcn_s_barrier();   // all waves done with Bd[kt&1]
            if (kt + 2 < 8) STAGE_B2(kt & 1, kt + 2);
        }

        // ============= epilogue ============================================
        __syncthreads();   // all MFMA reads done -> overlay Gs on [0,128K)
        {
            float (*G)[128] = wk ? Gs1 : Gs0;
#pragma unroll
            for (int mi = 0; mi < 4; ++mi)
#pragma unroll
                for (int ni = 0; ni < 4; ++ni)
#pragma unroll
                    for (int rr = 0; rr < 4; ++rr) {
                        const int gr = wm * 64 + mi * 16 + q * 4 + rr;
                        const int gc = wn * 64 + ni * 16 + r;
                        G[gr][gc ^ ((gr & 7) << 2)] = acc[mi][ni][rr];
                    }
        }
        __syncthreads();
        {
            const int sx = (row_e & 7) << 2;
            bf16_t hv[8];
            float yp = 0.f;
#pragma unroll
            for (int ii = 0; ii < 8; ++ii) {
                const int dl     = dq + ii;         // 0..31
                const int d_glob = nb * 32 + dl;
                const int c0x = (dl)      ^ sx;
                const int c1x = (32 + dl) ^ sx;
                const int c2x = (64 + dl) ^ sx;
                const int c3x = (96 + dl) ^ sx;
                float gi = Gs0[row_e][c0x] + Gs1[row_e][c0x] + b_gate[d_glob];
                float gf = Gs0[row_e][c1x] + Gs1[row_e][c1x] + b_gate[512  + d_glob];
                float gg = Gs0[row_e][c2x] + Gs1[row_e][c2x] + b_gate[1024 + d_glob];
                float go = Gs0[row_e][c3x] + Gs1[row_e][c3x] + b_gate[1536 + d_glob];
                float is = sigmoid_f(gi);
                float fs = sigmoid_f(gf);
                float os = sigmoid_f(go);
                float gt = tanh_f(gg);
                float c_new = fs * cv[ii] + is * gt;
                float hval  = os * tanh_f(c_new);
                cv[ii] = c_new;                      // cell state stays in regs
                hv[ii] = (bf16_t)hval;
                yp += hval * wo[ii];
            }
            *(bf16x8*)&Hout[(size_t)b_glob * 512 + nb * 32 + dq] = *(const bf16x8*)&hv[0];

            yp += __shfl_xor(yp, 1);
            yp += __shfl_xor(yp, 2);
            if ((tid & 3) == 0)
                atomicAdd(&yout[b_glob], yp + ((nb == 0) ? bo : 0.f));
        }

        // ============= group-local step barrier (16 blocks sharing mb) =====
        __syncthreads();               // all waves' stores issued & drained
        if (tid == 0) {
            __threadfence();           // release: make H/y visible (agent)
            atomicAdd(&bar[mb], 1u);
            if (!bailed) {
                const unsigned target = 16u * (unsigned)(t + 1);
                int spins = 0;
                while (__hip_atomic_load(&bar[mb], __ATOMIC_ACQUIRE,
                                         __HIP_MEMORY_SCOPE_AGENT) < target) {
                    __builtin_amdgcn_s_sleep(2);
                    if (++spins > (1 << 14)) { bailed = 1; break; }  // escape
                }
                __builtin_amdgcn_fence(__ATOMIC_ACQUIRE, "agent");
            }
        }
        __syncthreads();               // fan out; next step may start
    }
#undef STAGE_AB
#undef STAGE_B2
}

// ---------------------------------------------------------------------------
extern "C" void kernel_launch(void* const* d_in, const int* in_sizes, int n_in,
                              void* d_out, int out_size, void* d_ws, size_t ws_size,
                              hipStream_t stream) {
    const float* x     = (const float*)d_in[0];
    const float* h0    = (const float*)d_in[1];
    const float* c0    = (const float*)d_in[2];
    const float* y0    = (const float*)d_in[3];
    const float* W_in  = (const float*)d_in[4];
    const float* b_in  = (const float*)d_in[5];
    const float* W_ih  = (const float*)d_in[6];
    const float* W_hh  = (const float*)d_in[7];
    const float* b_ih  = (const float*)d_in[8];
    const float* b_hh  = (const float*)d_in[9];
    const float* W_out = (const float*)d_in[10];
    const float* b_out = (const float*)d_in[11];
    float* out = (float*)d_out;

    char* ws = (char*)d_ws;
    bf16_t*   Wcat  = (bf16_t*)(ws);                            // 4 MiB
    bf16_t*   Hb0   = (bf16_t*)(ws + (4u << 20));               // 2 MiB
    bf16_t*   Hb1   = (bf16_t*)(ws + (6u << 20));               // 2 MiB
    float*    bgate = (float*)(ws + (8u << 20));                // 8 KiB
    bf16_t*   Wbh   = (bf16_t*)(ws + (8u << 20) + (16u << 10)); // 32 KiB
    bf16_t*   Wbl   = (bf16_t*)(ws + (8u << 20) + (64u << 10)); // 32 KiB
    unsigned* bar   = (unsigned*)(ws + (8u << 20) + (128u << 10)); // 64 B

    prep_w    <<<2048, 256, 0, stream>>>(W_ih, W_hh, Wcat);
    prep_state<<<2048, 256, 0, stream>>>(h0, Hb0, out, bar);
    prep_bias <<<8,    256, 0, stream>>>(b_ih, b_hh, bgate);
    prep_wb   <<<64,   256, 0, stream>>>(W_in, Wbh, Wbl);

    step_persist<<<256, 512, 0, stream>>>(
        x, y0, Wbh, Wbl, b_in, c0, Hb0, Hb1, Wcat, bgate,
        W_out, b_out, out, bar);
    (void)in_sizes; (void)n_in; (void)out_size; (void)ws_size;
}

// Round 10
// 10193.711 us; speedup vs baseline: 2.8872x; 2.8872x over previous
//
#include <hip/hip_runtime.h>
#include <hip/hip_bf16.h>
#include <stdint.h>

#define SEQ   512
#define BATCH 2048
#define HID   512
#define XF    31

typedef __bf16 bf16_t;
typedef bf16_t bf16x8 __attribute__((ext_vector_type(8)));
typedef bf16_t bf16x4 __attribute__((ext_vector_type(4)));
typedef float  f32x4  __attribute__((ext_vector_type(4)));

// async global->LDS, 16B per lane; LDS dest = wave-uniform base + lane*16
__device__ __forceinline__ void gload16(const void* g, void* lds) {
    __builtin_amdgcn_global_load_lds(
        (const __attribute__((address_space(1))) void*)g,
        (__attribute__((address_space(3))) void*)lds,
        16, 0, 0);
}

__device__ __forceinline__ float sigmoid_f(float x) {
    return 1.f / (1.f + __expf(-x));
}
__device__ __forceinline__ float tanh_f(float x) {
    float e = __expf(2.f * x);
    return 1.f - 2.f / (e + 1.f);
}

// ---------------- prologue kernels (run once per launch) -------------------
__global__ void prep_w(const float* __restrict__ W_ih, const float* __restrict__ W_hh,
                       bf16_t* __restrict__ Wcat) {
    const int j = blockIdx.x;                 // 0..2047 (gate row)
    for (int k = threadIdx.x; k < 1024; k += 256) {
        float v = (k < 512) ? W_ih[(size_t)j * 512 + k]
                            : W_hh[(size_t)j * 512 + (k - 512)];
        Wcat[(size_t)j * 1024 + k] = (bf16_t)v;
    }
}

__global__ void prep_state(const float* __restrict__ h0, const float* __restrict__ c0,
                           bf16_t* __restrict__ H0, float* __restrict__ Cbuf,
                           float* __restrict__ out_all) {
    const int b = blockIdx.x;                 // 0..2047
    for (int d = threadIdx.x; d < 512; d += 256) {
        H0[(size_t)b * 512 + d]   = (bf16_t)h0[(size_t)b * 512 + d];
        Cbuf[(size_t)b * 512 + d] = c0[(size_t)b * 512 + d];
        out_all[(size_t)b * 512 + d] = 0.f;   // zero whole [SEQ][B] output
    }
}

__global__ void prep_bias(const float* __restrict__ b_ih, const float* __restrict__ b_hh,
                          float* __restrict__ bg) {
    int j = blockIdx.x * 256 + threadIdx.x;
    bg[j] = b_ih[j] + b_hh[j];
}

// W_in split into bf16 hi + lo residual (for f32-grade X0 via 3 MFMAs)
__global__ void prep_wb(const float* __restrict__ W_in,
                        bf16_t* __restrict__ Wbh, bf16_t* __restrict__ Wbl) {
    int idx = blockIdx.x * 256 + threadIdx.x;   // 0..16383 = 512*32
    float v = W_in[idx];
    bf16_t h = (bf16_t)v;
    Wbh[idx] = h;
    Wbl[idx] = (bf16_t)(v - (float)h);
}

// ---------------- fused per-step kernel ------------------------------------
// One launch per timestep (R9 showed persistence + agent fences blows L2
// every step: 72 MB/step HBM refetch, 2.6x slower — launch boundaries keep
// L2 warm). 256 blocks (XCD-stable 4x2 map), 512 thr = 8 waves
// (2m x 2n x 2k-split), 128x128 gate tile.
// R10 change vs R7 (counter-driven): epilogue cell-phase Gs reads were 64
// scalar ds_read_b32/thread with an 8-lanes-per-bank conflict (60% of the
// 6.7e8 SQ_LDS_BANK_CONFLICT measured in R9). Now f32x4 reads at
// g*32 + ((dq+4u)^sx) — bank-balanced (8 lanes per bank-quad) and 8x fewer
// LDS instructions. b_gate loads vectorized to float4.
__global__ __launch_bounds__(512, 1) void step_fused(
    const float*  __restrict__ x_t,    // [B][31] slice for this t
    const float*  __restrict__ yprev,  // [B] (y0 or out slice t-1)
    const bf16_t* __restrict__ Wbh,    // [512][32] bf16 hi
    const bf16_t* __restrict__ Wbl,    // [512][32] bf16 lo residual
    const float*  __restrict__ b_in,   // [512]
    const bf16_t* __restrict__ Hin,    // [B][512]
    bf16_t*       __restrict__ Hout,   // [B][512]
    float*        __restrict__ Cbuf,   // [B][512] fp32
    const bf16_t* __restrict__ Wcat,   // [2048][1024]
    const float*  __restrict__ b_gate, // [2048]
    const float*  __restrict__ W_out,  // [512]
    const float*  __restrict__ b_out,  // [1]
    float*        __restrict__ yout)   // out + t*B (pre-zeroed)
{
    __shared__ __align__(16) char smem[163840];
    // [0,131072): phase-1 As[4](@0)+Bs[4](@65536); then X0L[128][512] bf16;
    //             then Gs0(@0)/Gs1(@65536) f32 overlays
    // [131072,163840): phase-2 Bd[2] (16 KiB each)
    float (*Gs0)[128] = (float (*)[128])smem;
    float (*Gs1)[128] = (float (*)[128])(smem + 65536);

    const int tid  = threadIdx.x;
    const int lane = tid & 63;
    const int wid  = tid >> 6;        // 0..7
    const int wm   = wid >> 2;        // 0..1 (m half: 64 rows)
    const int wn   = (wid >> 1) & 1;  // 0..1 (n half: 64 cols)
    const int wk   = wid & 1;         // 0..1 (k half of BK=64)

    // XCD-stable decode: bid = xcd + 8*slot; XCD (xm,xn) on a 4x2 grid
    const int bid  = blockIdx.x;      // 0..255
    const int xcd  = bid & 7;
    const int slot = bid >> 3;        // 0..31
    const int mb   = (xcd >> 1) * 4 + (slot & 3);   // 0..15
    const int nb   = (xcd & 1) * 8 + (slot >> 2);   // 0..15

    const int r  = lane & 15, q = lane >> 4;
    const int lr  = lane >> 3;                        // row-in-8 for staging
    const int lcs = ((lane & 7) ^ lr) * 8;            // swizzled SOURCE k-chunk
    const int kob = (((wk << 2) + q) ^ (r & 7)) * 16; // swizzled read col (bytes)

    // ---- early: x(+y) B-fragments for ALL 8 batch groups, hi/lo split ----
    bf16x8 xh[8], xl[8];
#pragma unroll
    for (int g = 0; g < 8; ++g) {
        const int row = mb * 128 + g * 16 + r;
        const float* bp = x_t + (size_t)row * XF + q * 8;
        float tmp[8];
#pragma unroll
        for (int j = 0; j < 7; ++j) tmp[j] = bp[j];
        // k=31 slot: y(t-1); address-select avoids OOB read at the last row
        const float* p7 = (q == 3) ? (yprev + row) : (bp + 7);
        tmp[7] = *p7;
#pragma unroll
        for (int j = 0; j < 8; ++j) {
            bf16_t h = (bf16_t)tmp[j];
            xh[g][j] = h;
            xl[g][j] = (bf16_t)(tmp[j] - (float)h);
        }
    }

    f32x4 acc[4][4];
#pragma unroll
    for (int mi = 0; mi < 4; ++mi)
#pragma unroll
        for (int ni = 0; ni < 4; ++ni) {
            f32x4 z = {0.f, 0.f, 0.f, 0.f};
            acc[mi][ni] = z;
        }

    // stage A(Hin)+B(W_hh half) for kt in 8..15 into pipeline buffer dst
    auto stageAB = [&](int dst, int kt) {
        const int k0 = (kt - 8) * 64;
#pragma unroll
        for (int iss = 0; iss < 2; ++iss) {
            const int r0 = wid * 16 + iss * 8;
            gload16(Hin + (size_t)(mb * 128 + r0 + lr) * 512 + k0 + lcs,
                    smem + (size_t)dst * 16384 + r0 * 128);
        }
#pragma unroll
        for (int iss = 0; iss < 2; ++iss) {
            const int r0   = wid * 16 + iss * 8;
            const int nloc = r0 + lr;
            const int j    = (nloc >> 5) * 512 + nb * 32 + (nloc & 31);
            gload16(Wcat + (size_t)j * 1024 + kt * 64 + lcs,
                    smem + 65536 + (size_t)dst * 16384 + r0 * 128);
        }
    };
    // stage B(W_ih half) only, for kt in 0..7, into Bd[dst]
    auto stageB2 = [&](int dst, int kt) {
#pragma unroll
        for (int iss = 0; iss < 2; ++iss) {
            const int r0   = wid * 16 + iss * 8;
            const int nloc = r0 + lr;
            const int j    = (nloc >> 5) * 512 + nb * 32 + (nloc & 31);
            gload16(Wcat + (size_t)j * 1024 + kt * 64 + lcs,
                    smem + 131072 + (size_t)dst * 16384 + r0 * 128);
        }
    };

    // ================= phase 1: kt 8..15 (Hin x W_hh) ======================
    stageAB(0, 8);
    stageAB(1, 9);
#pragma unroll
    for (int kt = 8; kt < 16; ++kt) {
        if (kt + 2 < 16) stageAB((kt + 2) & 3, kt + 2);
        if (kt < 14) {
            asm volatile("s_waitcnt vmcnt(8)" ::: "memory");
        } else if (kt == 14) {
            asm volatile("s_waitcnt vmcnt(4)" ::: "memory");
        } else {
            asm volatile("s_waitcnt vmcnt(0)" ::: "memory");
        }
        __builtin_amdgcn_s_barrier();
        __builtin_amdgcn_sched_barrier(0);

        const int cur = kt & 3;
        const char* Ab = smem + (size_t)cur * 16384;
        const char* Bb = smem + 65536 + (size_t)cur * 16384;
        bf16x8 af[4], bfr[4];
#pragma unroll
        for (int mi = 0; mi < 4; ++mi)
            af[mi] = *(const bf16x8*)(Ab + (wm * 64 + mi * 16 + r) * 128 + kob);
#pragma unroll
        for (int ni = 0; ni < 4; ++ni)
            bfr[ni] = *(const bf16x8*)(Bb + (wn * 64 + ni * 16 + r) * 128 + kob);
#pragma unroll
        for (int mi = 0; mi < 4; ++mi)
#pragma unroll
            for (int ni = 0; ni < 4; ++ni)
                acc[mi][ni] = __builtin_amdgcn_mfma_f32_16x16x32_bf16(
                    af[mi], bfr[ni], acc[mi][ni], 0, 0, 0);
    }

    __syncthreads();   // all phase-1 LDS reads done; [0,128K) free for X0L

    // ================= phase B: build X0 slice in LDS ======================
    bf16x8 wfh[4], wfl[4];
    float4 bi4[4];
#pragma unroll
    for (int u = 0; u < 4; ++u) {
        const int dt = wid * 4 + u;
        const size_t wo_ = (size_t)(dt * 16 + r) * 32 + q * 8;
        wfh[u] = *(const bf16x8*)&Wbh[wo_];
        wfl[u] = *(const bf16x8*)&Wbl[wo_];
        bi4[u] = *(const float4*)&b_in[dt * 16 + q * 4];
    }
    stageB2(0, 0);
    stageB2(1, 1);

    // wave computes its 4 d-tiles x all 8 batch groups; 3-MFMA hi/lo split;
    // swizzled ds_write_b64 into X0L
#pragma unroll
    for (int u = 0; u < 4; ++u) {
        const int dt = wid * 4 + u;
#pragma unroll
        for (int g = 0; g < 8; ++g) {
            f32x4 pa = {0.f, 0.f, 0.f, 0.f};
            pa = __builtin_amdgcn_mfma_f32_16x16x32_bf16(wfh[u], xh[g], pa, 0, 0, 0);
            pa = __builtin_amdgcn_mfma_f32_16x16x32_bf16(wfh[u], xl[g], pa, 0, 0, 0);
            pa = __builtin_amdgcn_mfma_f32_16x16x32_bf16(wfl[u], xh[g], pa, 0, 0, 0);
            bf16x4 hv;
            hv[0] = (bf16_t)fmaxf(pa[0] + bi4[u].x, 0.f);
            hv[1] = (bf16_t)fmaxf(pa[1] + bi4[u].y, 0.f);
            hv[2] = (bf16_t)fmaxf(pa[2] + bi4[u].z, 0.f);
            hv[3] = (bf16_t)fmaxf(pa[3] + bi4[u].w, 0.f);
            const int c  = dt * 2 + (q >> 1);
            const int cs = (c & ~7) | ((c & 7) ^ (r & 7));
            *(bf16x4*)(smem + (size_t)(g * 16 + r) * 1024 + cs * 16 + (q & 1) * 8) = hv;
        }
    }

    __syncthreads();   // X0L complete (also drains Bd[0],Bd[1] staging)

    // ================= phase 2: kt 0..7 (X0 x W_ih) ========================
#pragma unroll
    for (int kt = 0; kt < 8; ++kt) {
        if (kt < 7) {
            asm volatile("s_waitcnt vmcnt(2)" ::: "memory");
        } else {
            asm volatile("s_waitcnt vmcnt(0)" ::: "memory");
        }
        __builtin_amdgcn_s_barrier();
        __builtin_amdgcn_sched_barrier(0);

        const char* Bb = smem + 131072 + (size_t)(kt & 1) * 16384;
        bf16x8 af[4], bfr[4];
#pragma unroll
        for (int mi = 0; mi < 4; ++mi)
            af[mi] = *(const bf16x8*)(smem + (size_t)(wm * 64 + mi * 16 + r) * 1024
                                      + kt * 128 + kob);
#pragma unroll
        for (int ni = 0; ni < 4; ++ni)
            bfr[ni] = *(const bf16x8*)(Bb + (wn * 64 + ni * 16 + r) * 128 + kob);
#pragma unroll
        for (int mi = 0; mi < 4; ++mi)
#pragma unroll
            for (int ni = 0; ni < 4; ++ni)
                acc[mi][ni] = __builtin_amdgcn_mfma_f32_16x16x32_bf16(
                    af[mi], bfr[ni], acc[mi][ni], 0, 0, 0);
        __builtin_amdgcn_s_barrier();   // all waves done with Bd[kt&1]
        if (kt + 2 < 8) stageB2(kt & 1, kt + 2);
    }

    // ================= epilogue ============================================
    const int row    = tid >> 2;          // 0..127
    const int dq     = (tid & 3) * 8;     // 0..24 (8 d's per thread)
    const int b_glob = mb * 128 + row;

    float cv[8], wo[8];
    *(float4*)&cv[0] = *(const float4*)&Cbuf[(size_t)b_glob * 512 + nb * 32 + dq];
    *(float4*)&cv[4] = *(const float4*)&Cbuf[(size_t)b_glob * 512 + nb * 32 + dq + 4];
    *(float4*)&wo[0] = *(const float4*)&W_out[nb * 32 + dq];
    *(float4*)&wo[4] = *(const float4*)&W_out[nb * 32 + dq + 4];
    const float bo = b_out[0];

    __syncthreads();   // all MFMA reads done -> overlay Gs on [0,128K)

    {
        float (*G)[128] = wk ? Gs1 : Gs0;
#pragma unroll
        for (int mi = 0; mi < 4; ++mi)
#pragma unroll
            for (int ni = 0; ni < 4; ++ni)
#pragma unroll
                for (int rr = 0; rr < 4; ++rr) {
                    const int gr = wm * 64 + mi * 16 + q * 4 + rr;
                    const int gc = wn * 64 + ni * 16 + r;
                    G[gr][gc ^ ((gr & 7) << 2)] = acc[mi][ni][rr];
                }
    }
    __syncthreads();

    {
        const int sx = (row & 7) << 2;
        // vectorized, bank-balanced Gs reads: since dq+4u is 4-aligned and
        // sx is a multiple of 4, (dl^sx) is contiguous within 4-blocks ->
        // f32x4 at g*32 + ((dq+4u)^sx) covers dl=dq+4u..+3 in order.
        float gv[4][8];
#pragma unroll
        for (int u = 0; u < 2; ++u) {
            const int cb = (dq + 4 * u) ^ sx;
#pragma unroll
            for (int g = 0; g < 4; ++g) {
                f32x4 a0 = *(const f32x4*)&Gs0[row][g * 32 + cb];
                f32x4 a1 = *(const f32x4*)&Gs1[row][g * 32 + cb];
#pragma unroll
                for (int j = 0; j < 4; ++j) gv[g][u * 4 + j] = a0[j] + a1[j];
            }
        }
        float bgv[4][8];
#pragma unroll
        for (int g = 0; g < 4; ++g) {
            *(float4*)&bgv[g][0] = *(const float4*)&b_gate[g * 512 + nb * 32 + dq];
            *(float4*)&bgv[g][4] = *(const float4*)&b_gate[g * 512 + nb * 32 + dq + 4];
        }
        float cnew[8];
        bf16_t hv[8];
        float yp = 0.f;
#pragma unroll
        for (int ii = 0; ii < 8; ++ii) {
            float is = sigmoid_f(gv[0][ii] + bgv[0][ii]);
            float fs = sigmoid_f(gv[1][ii] + bgv[1][ii]);
            float gt = tanh_f(gv[2][ii] + bgv[2][ii]);
            float os = sigmoid_f(gv[3][ii] + bgv[3][ii]);
            float c_new = fs * cv[ii] + is * gt;
            float hval  = os * tanh_f(c_new);
            cnew[ii] = c_new;
            hv[ii]   = (bf16_t)hval;
            yp += hval * wo[ii];
        }
        const size_t base = (size_t)b_glob * 512 + nb * 32 + dq;
        *(float4*)&Cbuf[base]     = *(const float4*)&cnew[0];
        *(float4*)&Cbuf[base + 4] = *(const float4*)&cnew[4];
        *(bf16x8*)&Hout[base]     = *(const bf16x8*)&hv[0];

        yp += __shfl_xor(yp, 1);
        yp += __shfl_xor(yp, 2);
        if ((tid & 3) == 0)
            atomicAdd(&yout[b_glob], yp + ((nb == 0) ? bo : 0.f));
    }
}

// ---------------------------------------------------------------------------
extern "C" void kernel_launch(void* const* d_in, const int* in_sizes, int n_in,
                              void* d_out, int out_size, void* d_ws, size_t ws_size,
                              hipStream_t stream) {
    const float* x     = (const float*)d_in[0];
    const float* h0    = (const float*)d_in[1];
    const float* c0    = (const float*)d_in[2];
    const float* y0    = (const float*)d_in[3];
    const float* W_in  = (const float*)d_in[4];
    const float* b_in  = (const float*)d_in[5];
    const float* W_ih  = (const float*)d_in[6];
    const float* W_hh  = (const float*)d_in[7];
    const float* b_ih  = (const float*)d_in[8];
    const float* b_hh  = (const float*)d_in[9];
    const float* W_out = (const float*)d_in[10];
    const float* b_out = (const float*)d_in[11];
    float* out = (float*)d_out;

    char* ws = (char*)d_ws;
    bf16_t* Wcat  = (bf16_t*)(ws);                         // 4 MiB [2048][1024]
    bf16_t* Hb0   = (bf16_t*)(ws + (4u << 20));            // 2 MiB
    bf16_t* Hb1   = (bf16_t*)(ws + (6u << 20));            // 2 MiB
    float*  Cbuf  = (float*)(ws + (8u << 20));             // 4 MiB
    float*  bgate = (float*)(ws + (12u << 20));            // 8 KiB
    bf16_t* Wbh   = (bf16_t*)(ws + (12u << 20) + (16u << 10));  // 32 KiB
    bf16_t* Wbl   = (bf16_t*)(ws + (12u << 20) + (64u << 10));  // 32 KiB
    bf16_t* Hb[2] = { Hb0, Hb1 };

    prep_w    <<<2048, 256, 0, stream>>>(W_ih, W_hh, Wcat);
    prep_state<<<2048, 256, 0, stream>>>(h0, c0, Hb[0], Cbuf, out);
    prep_bias <<<8,    256, 0, stream>>>(b_ih, b_hh, bgate);
    prep_wb   <<<64,   256, 0, stream>>>(W_in, Wbh, Wbl);

    for (int t = 0; t < SEQ; ++t) {
        const float* yprev = (t == 0) ? y0 : (out + (size_t)(t - 1) * BATCH);
        step_fused<<<256, 512, 0, stream>>>(
            x + (size_t)t * BATCH * XF, yprev, Wbh, Wbl, b_in,
            Hb[t & 1], Hb[(t + 1) & 1], Cbuf, Wcat, bgate, W_out, b_out,
            out + (size_t)t * BATCH);
    }
    (void)in_sizes; (void)n_in; (void)out_size; (void)ws_size;
}